// Round 6
// baseline (209.518 us; speedup 1.0000x reference)
//
#include <hip/hip_runtime.h>
#include <hip/hip_bf16.h>

typedef __hip_bfloat16 BF16;
typedef __attribute__((ext_vector_type(8))) short short8;
typedef __attribute__((ext_vector_type(4))) float f32x4;

#define MFMA_B16(a,b,c) __builtin_amdgcn_mfma_f32_16x16x32_bf16((a),(b),(c),0,0,0)

#if __has_builtin(__builtin_amdgcn_exp2f)
#define EXP2F(x) __builtin_amdgcn_exp2f(x)
#else
#define EXP2F(x) __expf(0.6931471805599453f * (x))
#endif

__device__ __forceinline__ short f2bs(float f){ BF16 h = __float2bfloat16(f); return *(short*)&h; }
__device__ __forceinline__ float bs2f(short s){ BF16 h = *(BF16*)&s; return __bfloat162float(h); }

struct FcPrepP {
    const float* X;
    const float* W0[2];
    const float* fcb[2];
    short* inH[2];
    const float* wsrc[8];
    short* wdst[8];
};
struct MbloDir { const short* Ah; const short* W1h; const short* W2h;
                 const float* mb; short* Hh; int fw; };
struct GDir { const void* A0; const void* Al; const short* Wh; const short* Wl;
              const float* bias; void* O0; };
struct PoolDir { const short* T1; const short* Wh; const float* bias;
                 const short* Hh; float* V; };
struct Gate2Dir { const float* V; const float* W1; const float* W2; const float* mb;
                  const float* gW1; const float* gW2; const float* gb;
                  float* E0; int fw; };
struct FuseDir { const short* INh; const short* Hh;
                 const float* E0; const float* fW1; const float* fb1;
                 const float* fW2; const float* fb2; };

// ============================================================================
// ====================  FALLBACK: proven 5-kernel chain  =====================
// ============================================================================

__global__ __launch_bounds__(256) void fcprep_k(FcPrepP P)
{
    __shared__ char SM[36864] __attribute__((aligned(16)));
    int job = blockIdx.x;
    int tid = threadIdx.x;

    if (job >= 512) {
        int mi = job - 512;
        int mat = mi >> 4, tile = mi & 15;
        float (*s)[65] = (float(*)[65])SM;
        const float* W = P.wsrc[mat];
        short* oh = P.wdst[mat];
        int tr = (tile >> 2) * 64, tc = (tile & 3) * 64;
        #pragma unroll
        for (int i = 0; i < 16; i++) {
            int e = tid + i * 256;
            int r = e >> 6, c = e & 63;
            s[c][r] = W[(size_t)(tr + r) * 256 + tc + c];
        }
        __syncthreads();
        #pragma unroll
        for (int i = 0; i < 16; i++) {
            int e = tid + i * 256;
            int c2 = e >> 6, r2 = e & 63;
            oh[(size_t)(tc + c2) * 256 + tr + r2] = f2bs(s[c2][r2]);
        }
        return;
    }

    short* sAh = (short*)SM;
    short* sAl = sAh + 4608;
    short* sBh = sAh + 9216;
    short* sBl = sAh + 13824;
    int dir = job >> 8, rem = job & 255;
    int row0 = (rem & 63) * 64, col0 = (rem >> 6) * 64;
    const float* W0 = P.W0[dir];
    const float* bias = P.fcb[dir];
    short* O = P.inH[dir];

    int w = tid >> 6, l = tid & 63;
    int m = l & 15, q = l >> 4;
    int sr = w * 16 + m;
    int bcc = tid >> 2, bkk0 = (tid & 3) * 16;

    f32x4 acc[4];
    #pragma unroll
    for (int cf = 0; cf < 4; cf++) acc[cf] = (f32x4)(0.f);

    for (int kh = 0; kh < 4; kh++) {
        int kbase = kh * 64;
        #pragma unroll
        for (int i = 0; i < 2; i++) {
            int kl = q * 8 + 32 * i;
            size_t gofs = (size_t)(row0 + sr) * 256 + kbase + kl;
            const float* src = P.X + gofs;
            float4 f0 = *(const float4*)src;
            float4 f1 = *(const float4*)(src + 4);
            short8 vh, vl;
            float tmp[8] = {f0.x, f0.y, f0.z, f0.w, f1.x, f1.y, f1.z, f1.w};
            #pragma unroll
            for (int j = 0; j < 8; j++) {
                vh[j] = f2bs(tmp[j]);
                vl[j] = f2bs(tmp[j] - bs2f(vh[j]));
            }
            *(short8*)&sAh[sr * 72 + kl] = vh;
            *(short8*)&sAl[sr * 72 + kl] = vl;
        }
        {
            float vals[16];
            #pragma unroll
            for (int j = 0; j < 16; j++)
                vals[j] = W0[(size_t)(kbase + bkk0 + j) * 256 + col0 + bcc];
            #pragma unroll
            for (int h8 = 0; h8 < 2; h8++) {
                short8 vh, vl;
                #pragma unroll
                for (int j = 0; j < 8; j++) {
                    float v = vals[h8 * 8 + j];
                    vh[j] = f2bs(v);
                    vl[j] = f2bs(v - bs2f(vh[j]));
                }
                *(short8*)&sBh[bcc * 72 + bkk0 + h8 * 8] = vh;
                *(short8*)&sBl[bcc * 72 + bkk0 + h8 * 8] = vl;
            }
        }
        __syncthreads();
        #pragma unroll
        for (int ch = 0; ch < 2; ch++) {
            int k = ch * 32 + q * 8;
            short8 ah = *(const short8*)&sAh[(w * 16 + m) * 72 + k];
            short8 al = *(const short8*)&sAl[(w * 16 + m) * 72 + k];
            #pragma unroll
            for (int cf = 0; cf < 4; cf++) {
                short8 bh = *(const short8*)&sBh[(cf * 16 + m) * 72 + k];
                acc[cf] = MFMA_B16(ah, bh, acc[cf]);
                short8 bl = *(const short8*)&sBl[(cf * 16 + m) * 72 + k];
                acc[cf] = MFMA_B16(ah, bl, acc[cf]);
                acc[cf] = MFMA_B16(al, bh, acc[cf]);
            }
        }
        __syncthreads();
    }
    #pragma unroll
    for (int cf = 0; cf < 4; cf++) {
        int col = col0 + cf * 16 + m;
        float bv = bias[col];
        #pragma unroll
        for (int r = 0; r < 4; r++) {
            int row = row0 + w * 16 + q * 4 + r;
            float v = fmaxf(acc[cf][r] + bv, 0.f);
            O[(size_t)row * 256 + col] = f2bs(v);
        }
    }
}

__global__ __launch_bounds__(512) void mblo_k(MbloDir p0, MbloDir p1)
{
    __shared__ char smraw[33536] __attribute__((aligned(16)));
    short* gAh  = (short*)smraw;
    short* gB1h = gAh + 4608;
    short* gB2h = gAh + 9216;
    float* aP   = (float*)smraw;
    unsigned int* aQX = (unsigned int*)(smraw + 16896);

    const float KLN = -0.06931471805599453f;

    MbloDir p = blockIdx.z ? p1 : p0;
    int tid = threadIdx.x;
    int w = tid >> 6, l = tid & 63;
    int m = l & 15, q = l >> 4;
    int rh = w >> 1;
    int cb = (w & 1) * 2;
    int bn = blockIdx.x >> 1, ipar = blockIdx.x & 1;
    int row0 = bn * 64, d0 = blockIdx.y * 64;
    int srow = tid >> 3;
    int skl  = (tid & 7) * 8;

    f32x4 acc1[2], acc2[2];
    #pragma unroll
    for (int cf = 0; cf < 2; cf++) { acc1[cf] = (f32x4)(0.f); acc2[cf] = (f32x4)(0.f); }

    for (int kh = 0; kh < 4; kh++) {
        int kbase = kh * 64;
        size_t ga = (size_t)(row0 + srow) * 256 + kbase + skl;
        *(short8*)&gAh[srow * 72 + skl] = *(const short8*)(p.Ah + ga);
        size_t gb = (size_t)(d0 + srow) * 256 + kbase + skl;
        *(short8*)&gB1h[srow * 72 + skl] = *(const short8*)(p.W1h + gb);
        *(short8*)&gB2h[srow * 72 + skl] = *(const short8*)(p.W2h + gb);
        __syncthreads();
        #pragma unroll
        for (int ch = 0; ch < 2; ch++) {
            int k = ch * 32 + q * 8;
            short8 ah = *(const short8*)&gAh[(rh * 16 + m) * 72 + k];
            #pragma unroll
            for (int cf = 0; cf < 2; cf++) {
                int bofs = ((cb + cf) * 16 + m) * 72 + k;
                short8 b1 = *(const short8*)&gB1h[bofs];
                acc1[cf] = MFMA_B16(ah, b1, acc1[cf]);
                short8 b2 = *(const short8*)&gB2h[bofs];
                acc2[cf] = MFMA_B16(ah, b2, acc2[cf]);
            }
        }
        __syncthreads();
    }
    short* sQX = (short*)aQX;
    #pragma unroll
    for (int cf = 0; cf < 2; cf++) {
        int col = (cb + cf) * 16 + m;
        float mbv = p.mb[d0 + col];
        #pragma unroll
        for (int r = 0; r < 4; r++) {
            int row = rh * 16 + q * 4 + r;
            aP[row * 66 + col] = __expf(0.4f * acc1[cf][r]) * KLN;
            sQX[col * 130 + 2 * row] = f2bs(__expf(0.4f * (acc2[cf][r] + mbv)));
        }
    }
    {
        size_t gx = (size_t)(row0 + srow) * 256 + d0 + skl;
        short8 xh = *(const short8*)(p.Ah + gx);
        #pragma unroll
        for (int t = 0; t < 8; t++)
            sQX[(skl + t) * 130 + 2 * srow + 1] = xh[t];
    }
    __syncthreads();
    const unsigned int* lane_qx = &aQX[l * 65];
    #pragma unroll
    for (int t8 = 0; t8 < 4; t8++) {
        int i = ipar + 2 * (w + 8 * t8);
        float Pp = aP[i * 66 + l];
        int js = p.fw ? (i + 1) : 0;
        int je = p.fw ? 64 : i;
        float den0 = 0.f, den1 = 0.f, num0 = 0.f, num1 = 0.f;
        int j = js;
        for (; j + 4 <= je; j += 4) {
            unsigned int u0 = lane_qx[j];
            unsigned int u1 = lane_qx[j + 1];
            unsigned int u2 = lane_qx[j + 2];
            unsigned int u3 = lane_qx[j + 3];
            float q0 = bs2f((short)(u0 & 0xffff)), x0 = bs2f((short)(u0 >> 16));
            float q1 = bs2f((short)(u1 & 0xffff)), x1 = bs2f((short)(u1 >> 16));
            float q2 = bs2f((short)(u2 & 0xffff)), x2 = bs2f((short)(u2 >> 16));
            float q3 = bs2f((short)(u3 & 0xffff)), x3 = bs2f((short)(u3 >> 16));
            float w0 = EXP2F(__builtin_amdgcn_rcpf(fmaf(Pp, q0, KLN)));
            float w1 = EXP2F(__builtin_amdgcn_rcpf(fmaf(Pp, q1, KLN)));
            float w2 = EXP2F(__builtin_amdgcn_rcpf(fmaf(Pp, q2, KLN)));
            float w3 = EXP2F(__builtin_amdgcn_rcpf(fmaf(Pp, q3, KLN)));
            den0 += w0; num0 = fmaf(w0, x0, num0);
            den1 += w1; num1 = fmaf(w1, x1, num1);
            den0 += w2; num0 = fmaf(w2, x2, num0);
            den1 += w3; num1 = fmaf(w3, x3, num1);
        }
        for (; j < je; j++) {
            unsigned int u0 = lane_qx[j];
            float q0 = bs2f((short)(u0 & 0xffff)), x0 = bs2f((short)(u0 >> 16));
            float wgt = EXP2F(__builtin_amdgcn_rcpf(fmaf(Pp, q0, KLN)));
            den0 += wgt; num0 = fmaf(wgt, x0, num0);
        }
        float den = den0 + den1, num = num0 + num1;
        bool valid = p.fw ? (i < 63) : (i > 0);
        float out = valid ? (num * __builtin_amdgcn_rcpf(den)) : 0.f;
        p.Hh[(size_t)(row0 + i) * 256 + d0 + l] = f2bs(out);
    }
}

struct S2TDir { const short* Hh; const short* W3h; const float* b1;
                const short* W4h; const float* b2; float* V; };

__global__ __launch_bounds__(512) void s2t_fused_k(S2TDir p0, S2TDir p1)
{
    __shared__ char smraw[79872] __attribute__((aligned(16)));
    short* sT1 = (short*)smraw;
    short* gA  = (short*)(smraw + 33792);
    short* gB  = (short*)(smraw + 43008);
    short* gB2 = (short*)(smraw + 33792);
    float* aL  = (float*)(smraw + 43008);
    float* rm  = (float*)(smraw + 60416);
    float* rd  = rm + 512;
    float* rn  = rm + 1024;

    S2TDir p = blockIdx.z ? p1 : p0;
    int tid = threadIdx.x;
    int w = tid >> 6, l = tid & 63;
    int m = l & 15, q = l >> 4;
    int row0 = blockIdx.x * 64;
    int d0 = blockIdx.y * 64;
    int strip = w >> 1, chalf = w & 1;
    int srow = tid >> 3, skl = (tid & 7) * 8;

    f32x4 acc1[8];
    #pragma unroll
    for (int cf = 0; cf < 8; cf++) acc1[cf] = (f32x4)(0.f);
    for (int kh = 0; kh < 4; kh++) {
        int kbase = kh * 64;
        *(short8*)&gA[srow * 72 + skl] =
            *(const short8*)(p.Hh + (size_t)(row0 + srow) * 256 + kbase + skl);
        int bn = tid >> 1;
        #pragma unroll
        for (int i = 0; i < 4; i++) {
            int kseg = (tid & 1) * 32 + i * 8;
            *(short8*)&gB[bn * 72 + kseg] =
                *(const short8*)(p.W3h + (size_t)bn * 256 + kbase + kseg);
        }
        __syncthreads();
        #pragma unroll
        for (int ch = 0; ch < 2; ch++) {
            int k = ch * 32 + q * 8;
            short8 ah = *(const short8*)&gA[(strip * 16 + m) * 72 + k];
            #pragma unroll
            for (int cf = 0; cf < 8; cf++) {
                short8 bh = *(const short8*)&gB[(chalf * 128 + cf * 16 + m) * 72 + k];
                acc1[cf] = MFMA_B16(ah, bh, acc1[cf]);
            }
        }
        __syncthreads();
    }
    #pragma unroll
    for (int cf = 0; cf < 8; cf++) {
        int col = chalf * 128 + cf * 16 + m;
        float bv = p.b1[col];
        #pragma unroll
        for (int r = 0; r < 4; r++) {
            int row = strip * 16 + q * 4 + r;
            sT1[row * 264 + col] = f2bs(fmaxf(acc1[cf][r] + bv, 0.f));
        }
    }
    __syncthreads();

    f32x4 acc2[2];
    acc2[0] = (f32x4)(0.f); acc2[1] = (f32x4)(0.f);
    for (int kh = 0; kh < 4; kh++) {
        int kbase = kh * 64;
        *(short8*)&gB2[srow * 72 + skl] =
            *(const short8*)(p.W4h + (size_t)(d0 + srow) * 256 + kbase + skl);
        __syncthreads();
        #pragma unroll
        for (int ch = 0; ch < 2; ch++) {
            int k = ch * 32 + q * 8;
            short8 ah = *(const short8*)&sT1[(strip * 16 + m) * 264 + kbase + k];
            #pragma unroll
            for (int cf = 0; cf < 2; cf++) {
                short8 bh = *(const short8*)&gB2[(chalf * 32 + cf * 16 + m) * 72 + k];
                acc2[cf] = MFMA_B16(ah, bh, acc2[cf]);
            }
        }
        __syncthreads();
    }
    #pragma unroll
    for (int cf = 0; cf < 2; cf++) {
        int col = chalf * 32 + cf * 16 + m;
        float bv = p.b2[d0 + col];
        #pragma unroll
        for (int r = 0; r < 4; r++) {
            int row = strip * 16 + q * 4 + r;
            aL[row * 68 + col] = acc2[cf][r] + bv;
        }
    }
    __syncthreads();
    int dl = tid & 63, rq = tid >> 6;
    float mx = -1e30f, den = 0.f, num = 0.f;
    #pragma unroll
    for (int rr = 0; rr < 8; rr++) {
        int r = rq * 8 + rr;
        float lv = aL[r * 68 + dl];
        float hv = bs2f(p.Hh[(size_t)(row0 + r) * 256 + d0 + dl]);
        if (lv > mx) { float sc = __expf(mx - lv); den *= sc; num *= sc; mx = lv; }
        float wgt = __expf(lv - mx);
        den += wgt; num = fmaf(wgt, hv, num);
    }
    rm[rq * 64 + dl] = mx; rd[rq * 64 + dl] = den; rn[rq * 64 + dl] = num;
    __syncthreads();
    if (rq == 0) {
        float M = rm[dl];
        #pragma unroll
        for (int kq = 1; kq < 8; kq++) M = fmaxf(M, rm[kq * 64 + dl]);
        float D = 0.f, Nn = 0.f;
        #pragma unroll
        for (int kq = 0; kq < 8; kq++) {
            float sc = __expf(rm[kq * 64 + dl] - M);
            D += rd[kq * 64 + dl] * sc;
            Nn += rn[kq * 64 + dl] * sc;
        }
        p.V[(size_t)blockIdx.x * 256 + d0 + dl] = Nn / D;
    }
}

__global__ __launch_bounds__(512) void attn2gate_k(Gate2Dir p0, Gate2Dir p1)
{
    Gate2Dir p = blockIdx.z ? p1 : p0;
    __shared__ __attribute__((aligned(16))) float sVT[4096];
    __shared__ float sPart[16][256];
    __shared__ float so[256], sv[256], red[8][64];
    int tid = threadIdx.x;
    int b = blockIdx.x;
    int k = tid & 255, half = tid >> 8;

    if (p.fw) {
        #pragma unroll
        for (int it = 0; it < 8; it++) {
            int e = tid + it * 512;
            int kk = e >> 4, j = e & 15;
            sVT[e] = p.V[(size_t)(b * 16 + j) * 256 + kk];
        }
        __syncthreads();
        float acc[16];
        #pragma unroll
        for (int j = 0; j < 16; j++) acc[j] = 0.f;
        int kk0 = half * 128;
        #pragma unroll 4
        for (int kk = kk0; kk < kk0 + 128; kk++) {
            const float4* vr = (const float4*)&sVT[kk * 16];
            float4 va = vr[0], vb = vr[1], vc = vr[2], vd = vr[3];
            float w1 = p.W1[(size_t)kk * 256 + k];
            float w2 = p.W2[(size_t)kk * 256 + k];
            acc[0]  = fmaf(va.x, w1, acc[0]);
            acc[1]  = fmaf(va.y, w2, acc[1]);
            acc[2]  = fmaf(va.z, w2, acc[2]);
            acc[3]  = fmaf(va.w, w2, acc[3]);
            acc[4]  = fmaf(vb.x, w2, acc[4]);
            acc[5]  = fmaf(vb.y, w2, acc[5]);
            acc[6]  = fmaf(vb.z, w2, acc[6]);
            acc[7]  = fmaf(vb.w, w2, acc[7]);
            acc[8]  = fmaf(vc.x, w2, acc[8]);
            acc[9]  = fmaf(vc.y, w2, acc[9]);
            acc[10] = fmaf(vc.z, w2, acc[10]);
            acc[11] = fmaf(vc.w, w2, acc[11]);
            acc[12] = fmaf(vd.x, w2, acc[12]);
            acc[13] = fmaf(vd.y, w2, acc[13]);
            acc[14] = fmaf(vd.z, w2, acc[14]);
            acc[15] = fmaf(vd.w, w2, acc[15]);
        }
        if (half) {
            #pragma unroll
            for (int j = 0; j < 16; j++) sPart[j][k] = acc[j];
        }
        __syncthreads();
        if (!half) {
            #pragma unroll
            for (int j = 0; j < 16; j++) acc[j] += sPart[j][k];
            float base = acc[0] + p.mb[k];
            float den = 0.f, num = 0.f;
            #pragma unroll
            for (int j = 1; j < 16; j++) {
                float z = (base + acc[j]) * 0.2f;
                float e2 = __expf(2.f * z);
                float t = 1.f - 2.f / (e2 + 1.f);
                float wgt = __expf(5.f * t);
                den += wgt;
                num = fmaf(wgt, p.V[(size_t)(b * 16 + j) * 256 + k], num);
            }
            so[k] = num / den;
            sv[k] = p.V[(size_t)(b * 16) * 256 + k];
        }
    } else {
        if (!half) {
            so[k] = 0.f;
            sv[k] = p.V[(size_t)(b * 16) * 256 + k];
        }
    }
    __syncthreads();
    int c = tid & 63, ks = tid >> 6;
    int gc = blockIdx.y * 64 + c;
    float a2 = 0.f;
    int k0 = ks * 32;
    #pragma unroll 8
    for (int kkx = 0; kkx < 32; kkx++) {
        int kx = k0 + kkx;
        a2 += so[kx] * p.gW1[(size_t)kx * 256 + gc] + sv[kx] * p.gW2[(size_t)kx * 256 + gc];
    }
    red[ks][c] = a2;
    __syncthreads();
    if (ks == 0) {
        float a = red[0][c] + red[1][c] + red[2][c] + red[3][c]
                + red[4][c] + red[5][c] + red[6][c] + red[7][c] + p.gb[gc];
        float G = 1.f / (1.f + __expf(-a));
        p.E0[b * 256 + gc] = G * so[gc] + (1.f - G) * sv[gc];
    }
}

__global__ __launch_bounds__(256) void fusion_k(FuseDir p0, FuseDir p1, float* __restrict__ out)
{
    FuseDir p = blockIdx.z ? p1 : p0;
    __shared__ float cat[768];
    __shared__ float red1[4][64], red2[4][64];
    int bt = blockIdx.x, b = bt >> 4, t = bt & 15;
    int c = threadIdx.x & 63, ks = threadIdx.x >> 6;
    int gc = blockIdx.y * 64 + c;
    size_t xrow = ((size_t)b * 1024 + t) * 256;
    cat[threadIdx.x]       = bs2f(p.INh[xrow + threadIdx.x]);
    cat[256 + threadIdx.x] = bs2f(p.Hh[xrow + threadIdx.x]);
    cat[512 + threadIdx.x] = p.E0[b * 256 + threadIdx.x];
    __syncthreads();
    float a1 = 0.f, a2 = 0.f;
    int k0 = ks * 192;
    #pragma unroll 8
    for (int kk = 0; kk < 192; kk++) {
        int k = k0 + kk;
        float cv = cat[k];
        a1 += cv * p.fW1[(size_t)k * 256 + gc];
        a2 += cv * p.fW2[(size_t)k * 256 + gc];
    }
    red1[ks][c] = a1; red2[ks][c] = a2;
    __syncthreads();
    if (ks == 0) {
        float s1 = red1[0][c] + red1[1][c] + red1[2][c] + red1[3][c] + p.fb1[gc];
        float s2 = red2[0][c] + red2[1][c] + red2[2][c] + red2[3][c] + p.fb2[gc];
        float fus = fmaxf(s1, 0.f);
        float Gf = 1.f / (1.f + __expf(-s2));
        float u = Gf * fus + (1.f - Gf) * cat[gc];
        out[((size_t)(b * 16 + t)) * 512 + (size_t)blockIdx.z * 256 + gc] = u;
    }
}

// ============================================================================
// ===========  PERSISTENT SINGLE-DISPATCH KERNEL, FAST BARRIERS  =============
// 512 blocks x 512 threads, 40 KB LDS (>=3 blk/CU by LDS, grid capped by
// occupancy query -> all blocks co-resident). 6 phases, 5 device-scope
// {count,flag} barriers (fresh pair per phase; zeroed by hipMemsetAsync).
// ============================================================================

struct PersP {
    const float* X;
    const float* W0[2]; const float* fcb[2]; short* inH[2];
    const float* wsrc[8]; short* wdst[8];
    MbloDir mbd[2];
    GDir s2t1[2];
    PoolDir pld[2];
    Gate2Dir gtd[2];
    FuseDir fsd[2];
    float* out;
    unsigned* bars;       // 5 x {cnt,flag}
};

__device__ __forceinline__ void gbar(unsigned* bar, int nb)
{
    __syncthreads();
    if (threadIdx.x == 0) {
        __threadfence();   // device-scope release of prior writes
        unsigned arrived = __hip_atomic_fetch_add(bar, 1u, __ATOMIC_ACQ_REL,
                                                  __HIP_MEMORY_SCOPE_AGENT) + 1u;
        if (arrived == (unsigned)nb) {
            __hip_atomic_store(bar + 1, 1u, __ATOMIC_RELEASE, __HIP_MEMORY_SCOPE_AGENT);
        } else {
            while (__hip_atomic_load(bar + 1, __ATOMIC_ACQUIRE,
                                     __HIP_MEMORY_SCOPE_AGENT) == 0u)
                __builtin_amdgcn_s_sleep(2);
        }
        __threadfence();   // acquire side
    }
    __syncthreads();
}

// 512-thread 64x64 GEMM (A single bf16 plane, B single plane, bf16+relu out)
__device__ __forceinline__ void gemm512_s(const short* __restrict__ A0,
    const short* __restrict__ Wh, const float* __restrict__ bias,
    short* __restrict__ O0, int row0, int col0, char* SM)
{
    short* sAh = (short*)SM;
    short* sBh = (short*)(SM + 18432);
    int tid = threadIdx.x;
    int w = tid >> 6, l = tid & 63, m = l & 15, q = l >> 4;
    int strip = w >> 1, chalf = w & 1;
    int srow = tid >> 3, skl = (tid & 7) * 8;
    f32x4 acc[2];
    acc[0] = (f32x4)(0.f); acc[1] = (f32x4)(0.f);
    for (int kh = 0; kh < 4; kh++) {
        int kb = kh * 64;
        size_t ga = (size_t)(row0 + srow) * 256 + kb + skl;
        *(short8*)&sAh[srow * 72 + skl] = *(const short8*)(A0 + ga);
        size_t gb = (size_t)(col0 + srow) * 256 + kb + skl;
        *(short8*)&sBh[srow * 72 + skl] = *(const short8*)(Wh + gb);
        __syncthreads();
        #pragma unroll
        for (int ch = 0; ch < 2; ch++) {
            int k = ch * 32 + q * 8;
            short8 ah = *(const short8*)&sAh[(strip * 16 + m) * 72 + k];
            #pragma unroll
            for (int cf = 0; cf < 2; cf++) {
                short8 bh = *(const short8*)&sBh[((chalf * 2 + cf) * 16 + m) * 72 + k];
                acc[cf] = MFMA_B16(ah, bh, acc[cf]);
            }
        }
        __syncthreads();
    }
    #pragma unroll
    for (int cf = 0; cf < 2; cf++) {
        int col = col0 + (chalf * 2 + cf) * 16 + m;
        float bv = bias[col];
        #pragma unroll
        for (int r = 0; r < 4; r++) {
            int row = row0 + strip * 16 + q * 4 + r;
            O0[(size_t)row * 256 + col] = f2bs(fmaxf(acc[cf][r] + bv, 0.f));
        }
    }
}

__global__ __launch_bounds__(512) void pers_k(PersP P)
{
    __shared__ char SM[40960] __attribute__((aligned(16)));
    const int tid = threadIdx.x;
    const int bid = blockIdx.x, nb = gridDim.x;
    const float KLN = -0.06931471805599453f;

    // ---------------- phase 1: fc GEMM + weight transposes ----------------
    for (int job = bid; job < 640; job += nb) {
        if (job >= 512) {
            int mi = job - 512;
            int mat = mi >> 4, tile = mi & 15;
            float (*s)[65] = (float(*)[65])SM;
            const float* W = P.wsrc[mat];
            short* oh = P.wdst[mat];
            int tr = (tile >> 2) * 64, tc = (tile & 3) * 64;
            #pragma unroll
            for (int i = 0; i < 8; i++) {
                int e = tid + i * 512;
                int r = e >> 6, c = e & 63;
                s[c][r] = W[(size_t)(tr + r) * 256 + tc + c];
            }
            __syncthreads();
            #pragma unroll
            for (int i = 0; i < 8; i++) {
                int e = tid + i * 512;
                int c2 = e >> 6, r2 = e & 63;
                oh[(size_t)(tc + c2) * 256 + tr + r2] = f2bs(s[c2][r2]);
            }
            __syncthreads();
            continue;
        }
        short* sAh = (short*)SM;
        short* sAl = sAh + 4608;
        short* sBh = sAh + 9216;
        short* sBl = sAh + 13824;
        int dir = job >> 8, rem = job & 255;
        int row0 = (rem & 63) * 64, col0 = (rem >> 6) * 64;
        const float* W0 = P.W0[dir];
        const float* bias = P.fcb[dir];
        short* O = P.inH[dir];
        int w = tid >> 6, l = tid & 63, m = l & 15, q = l >> 4;
        int strip = w >> 1, chalf = w & 1;
        int srow = tid >> 3, skl = (tid & 7) * 8;
        int bcc = tid >> 3, bkk0 = (tid & 7) * 8;
        f32x4 acc[2];
        acc[0] = (f32x4)(0.f); acc[1] = (f32x4)(0.f);
        for (int kh = 0; kh < 4; kh++) {
            int kbase = kh * 64;
            {
                size_t gofs = (size_t)(row0 + srow) * 256 + kbase + skl;
                const float* src = P.X + gofs;
                float4 f0 = *(const float4*)src;
                float4 f1 = *(const float4*)(src + 4);
                short8 vh, vl;
                float tmp[8] = {f0.x, f0.y, f0.z, f0.w, f1.x, f1.y, f1.z, f1.w};
                #pragma unroll
                for (int j = 0; j < 8; j++) {
                    vh[j] = f2bs(tmp[j]);
                    vl[j] = f2bs(tmp[j] - bs2f(vh[j]));
                }
                *(short8*)&sAh[srow * 72 + skl] = vh;
                *(short8*)&sAl[srow * 72 + skl] = vl;
            }
            {
                float vals[8];
                #pragma unroll
                for (int j = 0; j < 8; j++)
                    vals[j] = W0[(size_t)(kbase + bkk0 + j) * 256 + col0 + bcc];
                short8 vh, vl;
                #pragma unroll
                for (int j = 0; j < 8; j++) {
                    vh[j] = f2bs(vals[j]);
                    vl[j] = f2bs(vals[j] - bs2f(vh[j]));
                }
                *(short8*)&sBh[bcc * 72 + bkk0] = vh;
                *(short8*)&sBl[bcc * 72 + bkk0] = vl;
            }
            __syncthreads();
            #pragma unroll
            for (int ch = 0; ch < 2; ch++) {
                int k = ch * 32 + q * 8;
                short8 ah = *(const short8*)&sAh[(strip * 16 + m) * 72 + k];
                short8 al = *(const short8*)&sAl[(strip * 16 + m) * 72 + k];
                #pragma unroll
                for (int cf = 0; cf < 2; cf++) {
                    int bofs = ((chalf * 2 + cf) * 16 + m) * 72 + k;
                    short8 bh = *(const short8*)&sBh[bofs];
                    acc[cf] = MFMA_B16(ah, bh, acc[cf]);
                    short8 bl = *(const short8*)&sBl[bofs];
                    acc[cf] = MFMA_B16(ah, bl, acc[cf]);
                    acc[cf] = MFMA_B16(al, bh, acc[cf]);
                }
            }
            __syncthreads();
        }
        #pragma unroll
        for (int cf = 0; cf < 2; cf++) {
            int col = col0 + (chalf * 2 + cf) * 16 + m;
            float bv = bias[col];
            #pragma unroll
            for (int r = 0; r < 4; r++) {
                int row = row0 + strip * 16 + q * 4 + r;
                O[(size_t)row * 256 + col] = f2bs(fmaxf(acc[cf][r] + bv, 0.f));
            }
        }
    }
    gbar(P.bars + 0, nb);

    // ---------------- phase 2: MBLO ----------------
    {
        short* gAh  = (short*)SM;
        short* gB1h = gAh + 4608;
        short* gB2h = gAh + 9216;
        float* aP   = (float*)SM;
        unsigned int* aQX = (unsigned int*)(SM + 16896);
        int w = tid >> 6, l = tid & 63, m = l & 15, q = l >> 4;
        int rh = w >> 1, cb = (w & 1) * 2;
        int srow = tid >> 3, skl = (tid & 7) * 8;
        for (int job = bid; job < 512; job += nb) {
            int dir = job >> 8, rem = job & 255;
            MbloDir p = P.mbd[dir];
            int row0 = (rem & 63) * 64, d0 = (rem >> 6) * 64;
            f32x4 acc1[2], acc2[2];
            #pragma unroll
            for (int cf = 0; cf < 2; cf++) { acc1[cf] = (f32x4)(0.f); acc2[cf] = (f32x4)(0.f); }
            for (int kh = 0; kh < 4; kh++) {
                int kbase = kh * 64;
                size_t ga = (size_t)(row0 + srow) * 256 + kbase + skl;
                *(short8*)&gAh[srow * 72 + skl] = *(const short8*)(p.Ah + ga);
                size_t gb = (size_t)(d0 + srow) * 256 + kbase + skl;
                *(short8*)&gB1h[srow * 72 + skl] = *(const short8*)(p.W1h + gb);
                *(short8*)&gB2h[srow * 72 + skl] = *(const short8*)(p.W2h + gb);
                __syncthreads();
                #pragma unroll
                for (int ch = 0; ch < 2; ch++) {
                    int k = ch * 32 + q * 8;
                    short8 ah = *(const short8*)&gAh[(rh * 16 + m) * 72 + k];
                    #pragma unroll
                    for (int cf = 0; cf < 2; cf++) {
                        int bofs = ((cb + cf) * 16 + m) * 72 + k;
                        short8 b1 = *(const short8*)&gB1h[bofs];
                        acc1[cf] = MFMA_B16(ah, b1, acc1[cf]);
                        short8 b2 = *(const short8*)&gB2h[bofs];
                        acc2[cf] = MFMA_B16(ah, b2, acc2[cf]);
                    }
                }
                __syncthreads();
            }
            short* sQX = (short*)aQX;
            #pragma unroll
            for (int cf = 0; cf < 2; cf++) {
                int col = (cb + cf) * 16 + m;
                float mbv = p.mb[d0 + col];
                #pragma unroll
                for (int r = 0; r < 4; r++) {
                    int row = rh * 16 + q * 4 + r;
                    aP[row * 66 + col] = __expf(0.4f * acc1[cf][r]) * KLN;
                    sQX[col * 130 + 2 * row] = f2bs(__expf(0.4f * (acc2[cf][r] + mbv)));
                }
            }
            {
                size_t gx = (size_t)(row0 + srow) * 256 + d0 + skl;
                short8 xh = *(const short8*)(p.Ah + gx);
                #pragma unroll
                for (int t = 0; t < 8; t++)
                    sQX[(skl + t) * 130 + 2 * srow + 1] = xh[t];
            }
            __syncthreads();
            const unsigned int* lane_qx = &aQX[l * 65];
            for (int t8 = 0; t8 < 8; t8++) {
                int i = w + 8 * t8;
                float Pp = aP[i * 66 + l];
                int js = p.fw ? (i + 1) : 0;
                int je = p.fw ? 64 : i;
                float den0 = 0.f, den1 = 0.f, num0 = 0.f, num1 = 0.f;
                int j = js;
                for (; j + 4 <= je; j += 4) {
                    unsigned int u0 = lane_qx[j];
                    unsigned int u1 = lane_qx[j + 1];
                    unsigned int u2 = lane_qx[j + 2];
                    unsigned int u3 = lane_qx[j + 3];
                    float q0 = bs2f((short)(u0 & 0xffff)), x0 = bs2f((short)(u0 >> 16));
                    float q1 = bs2f((short)(u1 & 0xffff)), x1 = bs2f((short)(u1 >> 16));
                    float q2 = bs2f((short)(u2 & 0xffff)), x2 = bs2f((short)(u2 >> 16));
                    float q3 = bs2f((short)(u3 & 0xffff)), x3 = bs2f((short)(u3 >> 16));
                    float w0 = EXP2F(__builtin_amdgcn_rcpf(fmaf(Pp, q0, KLN)));
                    float w1 = EXP2F(__builtin_amdgcn_rcpf(fmaf(Pp, q1, KLN)));
                    float w2 = EXP2F(__builtin_amdgcn_rcpf(fmaf(Pp, q2, KLN)));
                    float w3 = EXP2F(__builtin_amdgcn_rcpf(fmaf(Pp, q3, KLN)));
                    den0 += w0; num0 = fmaf(w0, x0, num0);
                    den1 += w1; num1 = fmaf(w1, x1, num1);
                    den0 += w2; num0 = fmaf(w2, x2, num0);
                    den1 += w3; num1 = fmaf(w3, x3, num1);
                }
                for (; j < je; j++) {
                    unsigned int u0 = lane_qx[j];
                    float q0 = bs2f((short)(u0 & 0xffff)), x0 = bs2f((short)(u0 >> 16));
                    float wgt = EXP2F(__builtin_amdgcn_rcpf(fmaf(Pp, q0, KLN)));
                    den0 += wgt; num0 = fmaf(wgt, x0, num0);
                }
                float den = den0 + den1, num = num0 + num1;
                bool valid = p.fw ? (i < 63) : (i > 0);
                float out = valid ? (num * __builtin_amdgcn_rcpf(den)) : 0.f;
                p.Hh[(size_t)(row0 + i) * 256 + d0 + l] = f2bs(out);
            }
            __syncthreads();
        }
    }
    gbar(P.bars + 2, nb);

    // ---------------- phase 3: S2T1 ----------------
    for (int job = bid; job < 512; job += nb) {
        int dir = job >> 8, rem = job & 255;
        GDir p = P.s2t1[dir];
        gemm512_s((const short*)p.A0, p.Wh, p.bias, (short*)p.O0,
                  (rem & 63) * 64, (rem >> 6) * 64, SM);
    }
    gbar(P.bars + 4, nb);

    // ---------------- phase 4: POOL ----------------
    {
        short* gAh = (short*)SM;
        short* gBh = gAh + 4608;
        float* aL = (float*)SM;
        float* aH = aL + 4352;
        float* rm = (float*)(SM + 34816);
        float* rd = rm + 512;
        float* rn = rm + 1024;
        int w = tid >> 6, l = tid & 63, m = l & 15, q = l >> 4;
        int strip = w >> 1, chalf = w & 1;
        int srow = tid >> 3, skl = (tid & 7) * 8;
        for (int job = bid; job < 512; job += nb) {
            int dir = job >> 8, rem = job & 255;
            PoolDir p = P.pld[dir];
            int row0 = (rem & 63) * 64, d0 = (rem >> 6) * 64;
            f32x4 acc[2];
            acc[0] = (f32x4)(0.f); acc[1] = (f32x4)(0.f);
            for (int kh = 0; kh < 4; kh++) {
                int kbase = kh * 64;
                *(short8*)&gAh[srow * 72 + skl] =
                    *(const short8*)(p.T1 + (size_t)(row0 + srow) * 256 + kbase + skl);
                *(short8*)&gBh[srow * 72 + skl] =
                    *(const short8*)(p.Wh + (size_t)(d0 + srow) * 256 + kbase + skl);
                __syncthreads();
                #pragma unroll
                for (int ch = 0; ch < 2; ch++) {
                    int k = ch * 32 + q * 8;
                    short8 ah = *(const short8*)&gAh[(strip * 16 + m) * 72 + k];
                    #pragma unroll
                    for (int cf = 0; cf < 2; cf++) {
                        short8 bh = *(const short8*)&gBh[((chalf * 2 + cf) * 16 + m) * 72 + k];
                        acc[cf] = MFMA_B16(ah, bh, acc[cf]);
                    }
                }
                __syncthreads();
            }
            #pragma unroll
            for (int cf = 0; cf < 2; cf++) {
                int col = (chalf * 2 + cf) * 16 + m;
                float bv = p.bias[d0 + col];
                #pragma unroll
                for (int r = 0; r < 4; r++) {
                    int row = strip * 16 + q * 4 + r;
                    aL[row * 68 + col] = acc[cf][r] + bv;
                }
            }
            {
                int j = tid >> 3, d8 = (tid & 7) * 8;
                short8 xh = *(const short8*)(p.Hh + (size_t)(row0 + j) * 256 + d0 + d8);
                #pragma unroll
                for (int t = 0; t < 8; t++)
                    aH[j * 68 + d8 + t] = bs2f(xh[t]);
            }
            __syncthreads();
            int dl = tid & 63, rq = tid >> 6;
            float mx = -1e30f, den = 0.f, num = 0.f;
            #pragma unroll
            for (int rr = 0; rr < 8; rr++) {
                int r = rq * 8 + rr;
                float lv = aL[r * 68 + dl];
                float hv = aH[r * 68 + dl];
                if (lv > mx) { float sc = __expf(mx - lv); den *= sc; num *= sc; mx = lv; }
                float wgt = __expf(lv - mx);
                den += wgt; num = fmaf(wgt, hv, num);
            }
            rm[rq * 64 + dl] = mx; rd[rq * 64 + dl] = den; rn[rq * 64 + dl] = num;
            __syncthreads();
            if (rq == 0) {
                float M = rm[dl];
                #pragma unroll
                for (int kq = 1; kq < 8; kq++) M = fmaxf(M, rm[kq * 64 + dl]);
                float D = 0.f, Nn = 0.f;
                #pragma unroll
                for (int kq = 0; kq < 8; kq++) {
                    float sc = __expf(rm[kq * 64 + dl] - M);
                    D += rd[kq * 64 + dl] * sc;
                    Nn += rn[kq * 64 + dl] * sc;
                }
                p.V[(size_t)(rem & 63) * 256 + d0 + dl] = Nn / D;
            }
            __syncthreads();
        }
    }
    gbar(P.bars + 6, nb);

    // ---------------- phase 5: ATTN2 + gate ----------------
    {
        float* sVT = (float*)SM;
        float (*sPart)[256] = (float(*)[256])(SM + 16384);
        float* so = (float*)(SM + 32768);
        float* sv = (float*)(SM + 33792);
        float (*red)[64] = (float(*)[64])(SM + 34816);
        for (int job = bid; job < 32; job += nb) {
            int b = job & 3, gy = (job >> 2) & 3, dir = job >> 4;
            Gate2Dir p = P.gtd[dir];
            int k = tid & 255, half = tid >> 8;
            if (p.fw) {
                #pragma unroll
                for (int it = 0; it < 8; it++) {
                    int e = tid + it * 512;
                    int kk = e >> 4, j = e & 15;
                    sVT[e] = p.V[(size_t)(b * 16 + j) * 256 + kk];
                }
                __syncthreads();
                float acc[16];
                #pragma unroll
                for (int j = 0; j < 16; j++) acc[j] = 0.f;
                int kk0 = half * 128;
                #pragma unroll 4
                for (int kk = kk0; kk < kk0 + 128; kk++) {
                    const float4* vr = (const float4*)&sVT[kk * 16];
                    float4 va = vr[0], vb = vr[1], vc = vr[2], vd = vr[3];
                    float w1 = p.W1[(size_t)kk * 256 + k];
                    float w2 = p.W2[(size_t)kk * 256 + k];
                    acc[0]  = fmaf(va.x, w1, acc[0]);
                    acc[1]  = fmaf(va.y, w2, acc[1]);
                    acc[2]  = fmaf(va.z, w2, acc[2]);
                    acc[3]  = fmaf(va.w, w2, acc[3]);
                    acc[4]  = fmaf(vb.x, w2, acc[4]);
                    acc[5]  = fmaf(vb.y, w2, acc[5]);
                    acc[6]  = fmaf(vb.z, w2, acc[6]);
                    acc[7]  = fmaf(vb.w, w2, acc[7]);
                    acc[8]  = fmaf(vc.x, w2, acc[8]);
                    acc[9]  = fmaf(vc.y, w2, acc[9]);
                    acc[10] = fmaf(vc.z, w2, acc[10]);
                    acc[11] = fmaf(vc.w, w2, acc[11]);
                    acc[12] = fmaf(vd.x, w2, acc[12]);
                    acc[13] = fmaf(vd.y, w2, acc[13]);
                    acc[14] = fmaf(vd.z, w2, acc[14]);
                    acc[15] = fmaf(vd.w, w2, acc[15]);
                }
                if (half) {
                    #pragma unroll
                    for (int j = 0; j < 16; j++) sPart[j][k] = acc[j];
                }
                __syncthreads();
                if (!half) {
                    #pragma unroll
                    for (int j = 0; j < 16; j++) acc[j] += sPart[j][k];
                    float base = acc[0] + p.mb[k];
                    float den = 0.f, num = 0.f;
                    #pragma unroll
                    for (int j = 1; j < 16; j++) {
                        float z = (base + acc[j]) * 0.2f;
                        float e2 = __expf(2.f * z);
                        float t = 1.f - 2.f / (e2 + 1.f);
                        float wgt = __expf(5.f * t);
                        den += wgt;
                        num = fmaf(wgt, p.V[(size_t)(b * 16 + j) * 256 + k], num);
                    }
                    so[k] = num / den;
                    sv[k] = p.V[(size_t)(b * 16) * 256 + k];
                }
            } else {
                if (!half) {
                    so[k] = 0.f;
                    sv[k] = p.V[(size_t)(b * 16) * 256 + k];
                }
            }
            __syncthreads();
            int c = tid & 63, ks = tid >> 6;
            int gc = gy * 64 + c;
            float a2 = 0.f;
            int k0 = ks * 32;
            #pragma unroll 8
            for (int kkx = 0; kkx < 32; kkx++) {
                int kx = k0 + kkx;
                a2 += so[kx] * p.gW1[(size_t)kx * 256 + gc] + sv[kx] * p.gW2[(size_t)kx * 256 + gc];
            }
            red[ks][c] = a2;
            __syncthreads();
            if (ks == 0) {
                float a = red[0][c] + red[1][c] + red[2][c] + red[3][c]
                        + red[4][c] + red[5][c] + red[6][c] + red[7][c] + p.gb[gc];
                float G = 1.f / (1.f + __expf(-a));
                p.E0[b * 256 + gc] = G * so[gc] + (1.f - G) * sv[gc];
            }
            __syncthreads();
        }
    }
    gbar(P.bars + 8, nb);

    // ---------------- phase 6: FUSION ----------------
    {
        float* cat = (float*)SM;
        float (*red1)[64] = (float(*)[64])(SM + 3072);
        float (*red2)[64] = (float(*)[64])(SM + 5120);
        for (int job = bid; job < 512; job += nb) {
            int dir = job >> 8, rem = job & 255;
            int bt = rem & 63, gy = rem >> 6;
            FuseDir p = P.fsd[dir];
            int b = bt >> 4, t = bt & 15;
            size_t xrow = ((size_t)b * 1024 + t) * 256;
            if (tid < 256) {
                cat[tid] = bs2f(p.INh[xrow + tid]);
                cat[512 + tid] = p.E0[b * 256 + tid];
            } else {
                cat[tid] = bs2f(p.Hh[xrow + tid - 256]);
            }
            __syncthreads();
            int c = tid & 63, ks = tid >> 6;
            int gc = gy * 64 + c;
            float a1 = 0.f, a2 = 0.f;
            int k0 = ks * 96;
            #pragma unroll 8
            for (int kk = 0; kk < 96; kk++) {
                int k = k0 + kk;
                float cv = cat[k];
                a1 += cv * p.fW1[(size_t)k * 256 + gc];
                a2 += cv * p.fW2[(size_t)k * 256 + gc];
            }
            red1[ks][c] = a1; red2[ks][c] = a2;
            __syncthreads();
            if (ks == 0) {
                float s1 = p.fb1[gc], s2 = p.fb2[gc];
                #pragma unroll
                for (int kq = 0; kq < 8; kq++) { s1 += red1[kq][c]; s2 += red2[kq][c]; }
                float fus = fmaxf(s1, 0.f);
                float Gf = 1.f / (1.f + __expf(-s2));
                float u = Gf * fus + (1.f - Gf) * cat[gc];
                P.out[((size_t)(b * 16 + t)) * 512 + (size_t)dir * 256 + gc] = u;
            }
            __syncthreads();
        }
    }
}

// ============================================================================

extern "C" void kernel_launch(void* const* d_in, const int* in_sizes, int n_in,
                              void* d_out, int out_size, void* d_ws, size_t ws_size,
                              hipStream_t stream)
{
    const float* x = (const float*)d_in[0];
    char* base = (char*)d_ws;
    auto alloc = [&](size_t bytes){ void* r = base; base += (bytes + 255) & ~255ULL; return r; };
    short* inH = (short*)alloc(2 * 1048576 * 2);
    short* hH  = (short*)alloc(2 * 1048576 * 2);
    short* t1  = (short*)alloc(2 * 1048576 * 2);
    short* wtH = (short*)alloc(10 * 65536 * 2);
    float* v   = (float*)alloc(2 * 16384 * 4);
    float* E0  = (float*)alloc(2 * 1024 * 4);
    unsigned* bars = (unsigned*)alloc(256);

    FcPrepP fp;
    fp.X = x;
    const int wsrc_idx[4] = {2, 3, 5, 7};      // mW1, mW2, s2tW1, s2tW
    for (int p = 0; p < 2; p++) {
        int bi = 1 + p * 16;
        fp.W0[p]  = (const float*)d_in[bi + 0];
        fp.fcb[p] = (const float*)d_in[bi + 1];
        fp.inH[p] = inH + (size_t)p * 1048576;
        for (int wi = 0; wi < 4; wi++) {
            fp.wsrc[p * 4 + wi] = (const float*)d_in[bi + wsrc_idx[wi]];
            fp.wdst[p * 4 + wi] = wtH + (size_t)(p * 5 + 1 + wi) * 65536;
        }
    }

    MbloDir mbd[2];
    GDir s2t1[2];
    S2TDir std_[2];
    PoolDir pld[2];
    Gate2Dir gtd[2];
    FuseDir fsd[2];
    for (int p = 0; p < 2; p++) {
        int bi = 1 + p * 16;
        const float* mb    = (const float*)d_in[bi + 4];
        const float* s2tb1 = (const float*)d_in[bi + 6];
        const float* s2tb  = (const float*)d_in[bi + 8];
        size_t po = (size_t)p * 1048576;
        const short* W1h = wtH + (size_t)(p * 5 + 1) * 65536;
        const short* W2h = wtH + (size_t)(p * 5 + 2) * 65536;
        const short* W3h = wtH + (size_t)(p * 5 + 3) * 65536;
        const short* W4h = wtH + (size_t)(p * 5 + 4) * 65536;

        mbd[p]  = { inH + po, W1h, W2h, mb, hH + po, (p == 0) };
        s2t1[p] = { hH + po, nullptr, W3h, nullptr, s2tb1, t1 + po };
        std_[p] = { hH + po, W3h, s2tb1, W4h, s2tb, v + p * 16384 };
        pld[p]  = { t1 + po, W4h, s2tb, hH + po, v + p * 16384 };
        gtd[p]  = { v + p * 16384,
                    (const float*)d_in[bi + 2], (const float*)d_in[bi + 3], mb,
                    (const float*)d_in[bi + 9], (const float*)d_in[bi + 10],
                    (const float*)d_in[bi + 11], E0 + p * 1024, (p == 0) };
        fsd[p]  = { inH + po, hH + po, E0 + p * 1024,
                    (const float*)d_in[bi + 12], (const float*)d_in[bi + 13],
                    (const float*)d_in[bi + 14], (const float*)d_in[bi + 15] };
    }

    // size the persistent grid by occupancy (co-residency guarantee)
    static int persGrid = -2;
    if (persGrid == -2) {
        int perCU = 0;
        if (hipOccupancyMaxActiveBlocksPerMultiprocessor(&perCU, pers_k, 512, 0)
                == hipSuccess && perCU > 0) {
            hipDeviceProp_t prop;
            int dev = 0;
            hipGetDevice(&dev);
            if (hipGetDeviceProperties(&prop, dev) == hipSuccess) {
                long cap = (long)perCU * prop.multiProcessorCount;
                persGrid = (int)(cap < 512 ? cap : 512);
            } else persGrid = -1;
        } else persGrid = -1;
    }

    if (persGrid > 0) {
        hipMemsetAsync((void*)bars, 0, 64, stream);
        PersP P;
        P.X = x;
        for (int p = 0; p < 2; p++) {
            P.W0[p] = fp.W0[p]; P.fcb[p] = fp.fcb[p]; P.inH[p] = fp.inH[p];
            P.mbd[p] = mbd[p]; P.s2t1[p] = s2t1[p]; P.pld[p] = pld[p];
            P.gtd[p] = gtd[p]; P.fsd[p] = fsd[p];
        }
        for (int i = 0; i < 8; i++) { P.wsrc[i] = fp.wsrc[i]; P.wdst[i] = fp.wdst[i]; }
        P.out = (float*)d_out;
        P.bars = bars;
        pers_k<<<dim3(persGrid), 512, 0, stream>>>(P);
    } else {
        fcprep_k<<<dim3(640), 256, 0, stream>>>(fp);
        mblo_k<<<dim3(128, 4, 2), 512, 0, stream>>>(mbd[0], mbd[1]);
        s2t_fused_k<<<dim3(64, 4, 2), 512, 0, stream>>>(std_[0], std_[1]);
        attn2gate_k<<<dim3(4, 4, 2), 512, 0, stream>>>(gtd[0], gtd[1]);
        fusion_k<<<dim3(64, 4, 2), 256, 0, stream>>>(fsd[0], fsd[1], (float*)d_out);
    }
}